// Round 2
// baseline (231.094 us; speedup 1.0000x reference)
//
#include <hip/hip_runtime.h>

// FWHT over last dim 4096 of fp32, rows = total/4096.
// Radix-16^3: one 256-thread block per row-iteration, 16 floats/thread,
// three 4-bit register FWHT phases (bits 0-3, 4-7, 8-11) with two pitch-17
// LDS transposes. Butterfly order/pairing identical to the float32
// reference (h = 1..2048 ascending) -> bit-exact output (absmax = 0).
//
// v3 change (theory: latency-bound, not occupancy-bound — v2's 32-wave/CU
// restructure was neutral at ~78 us / 2.5 TB/s with all pipes idle):
// persistent blocks + cross-row software pipelining. Grid = 2048 blocks
// (~resident capacity), each block loops over nrows/2048 rows and issues
// the NEXT row's global loads right after phase B, so HBM reads are in
// flight under T2 + phase C + store + next phase A in every resident
// block. Stores are non-temporal (output never re-read; don't evict the
// input from L2/L3).
//
// LDS layouts (pitch 17 floats per 16-float row, measured 0 bank conflicts):
//   T1: element n at buf[17*(n>>4) + (n&15)]
//   T2: element n at buf[17*(n&255) + (n>>8)]

constexpr int DIM = 4096;
constexpr int PITCH = 17;      // floats per 16-float LDS row (+1 pad)
constexpr int NBLOCKS = 2048;  // 8 blocks/CU * 256 CUs; persistent grid

__device__ __forceinline__ void fwht16(float v[16]) {
#pragma unroll
    for (int h = 1; h < 16; h <<= 1) {
#pragma unroll
        for (int i = 0; i < 16; i += 2 * h) {
#pragma unroll
            for (int k = 0; k < h; ++k) {
                float a = v[i + k];
                float b = v[i + k + h];
                v[i + k]     = a + b;
                v[i + k + h] = a - b;
            }
        }
    }
}

__global__ __launch_bounds__(256, 8) void fwht4096_kernel(const float* __restrict__ x,
                                                          float* __restrict__ y,
                                                          int nrows) {
    __shared__ float buf[PITCH * 256];     // 17,408 B
    const int t = threadIdx.x;             // 0..255
    const int t_hi = t >> 4;
    const int t_lo = t & 15;

    // ---- prologue: issue loads for this block's first row ----
    float4 nxt[4];
    long long row = blockIdx.x;
    if (row < nrows) {
        const float4* src = reinterpret_cast<const float4*>(x + row * DIM + t * 16);
#pragma unroll
        for (int q = 0; q < 4; ++q) nxt[q] = src[q];
    }

    for (; row < nrows; row += NBLOCKS) {
        float v[16];
        // unpack the in-flight loads (compiler places the vmcnt wait here)
#pragma unroll
        for (int q = 0; q < 4; ++q) {
            v[4 * q + 0] = nxt[q].x;
            v[4 * q + 1] = nxt[q].y;
            v[4 * q + 2] = nxt[q].z;
            v[4 * q + 3] = nxt[q].w;
        }

        // ---- phase A: bits 0..3 (register index j; n = 16t + j) ----
        fwht16(v);

        __syncthreads();  // previous iteration's T2 reads done before reuse

        // ---- transpose 1: write n = 16t + j at 17t + j (4x b128-able) ----
        {
            float* wp = buf + PITCH * t;
#pragma unroll
            for (int j = 0; j < 16; ++j) wp[j] = v[j];
        }
        __syncthreads();
        // read n' = (t_hi<<8)|(j<<4)|t_lo  ->  272*t_hi + 17*j + t_lo
        {
            const float* rp = buf + (PITCH * 16) * t_hi + t_lo;
#pragma unroll
            for (int j = 0; j < 16; ++j) v[j] = rp[PITCH * j];
        }

        // ---- phase B: bits 4..7 ----
        fwht16(v);

        // ---- software pipeline: issue NEXT row's loads now ----
        {
            const long long nrow = row + NBLOCKS;
            if (nrow < nrows) {
                const float4* src =
                    reinterpret_cast<const float4*>(x + nrow * DIM + t * 16);
#pragma unroll
                for (int q = 0; q < 4; ++q) nxt[q] = src[q];
            }
        }

        __syncthreads();  // all T1 reads done before relayout

        // ---- transpose 2: value j (n' = (t_hi<<8)|(j<<4)|t_lo) at
        //      17*(n'&255) + (n'>>8) = 272*j + 17*t_lo + t_hi ----
        {
            float* wp = buf + PITCH * t_lo + t_hi;
#pragma unroll
            for (int j = 0; j < 16; ++j) wp[(PITCH * 16) * j] = v[j];
        }
        __syncthreads();
        // read n'' = (j<<8) | t  ->  17*t + j (contiguous)
        {
            const float* rp = buf + PITCH * t;
#pragma unroll
            for (int j = 0; j < 16; ++j) v[j] = rp[j];
        }

        // ---- phase C: bits 8..11 ----
        fwht16(v);

        // ---- scale + nontemporal store: value j at n = j*256 + t ----
        const float scale = 0x1p-39f;  // 2^-(L(L+1)/4), L = 12
        float* dst = y + row * DIM + t;
#pragma unroll
        for (int j = 0; j < 16; ++j) {
            __builtin_nontemporal_store(v[j] * scale, dst + j * 256);
        }
    }
}

extern "C" void kernel_launch(void* const* d_in, const int* in_sizes, int n_in,
                              void* d_out, int out_size, void* d_ws, size_t ws_size,
                              hipStream_t stream) {
    const float* x = (const float*)d_in[0];
    float* y = (float*)d_out;
    const int nrows = in_sizes[0] / DIM;  // 8192
    const int grid = nrows < NBLOCKS ? nrows : NBLOCKS;
    fwht4096_kernel<<<grid, 256, 0, stream>>>(x, y, nrows);
}

// Round 4
// 231.048 us; speedup vs baseline: 1.0002x; 1.0002x over previous
//
#include <hip/hip_runtime.h>

// FWHT over last dim 4096 of fp32, rows = total/4096.
// Radix-16^3: one 256-thread block per row-iteration, 16 floats/thread,
// three 4-bit register FWHT phases (bits 0-3, 4-7, 8-11) with two pitch-17
// LDS transposes. Butterfly order/pairing identical to the float32
// reference (h = 1..2048 ascending) -> bit-exact output (absmax = 0).
//
// v5: latency fix via global_load_lds (m97/T3 pattern). v3's compiler-
// visible prefetch was sunk (VGPR=28 proved it); v4's asm-register
// prefetch crashed (regalloc hazards on in-flight asm dests). glds has
// NO destination VGPRs -> nothing to sink/copy/spill. Each wave DMAs the
// next row's quarter into a linear LDS staging buffer right after phase A,
// and waits at next loop top with a counted `s_waitcnt vmcnt(16)` (the 4
// glds are the oldest outstanding ops; the 16 newer nt-stores may remain
// in flight). Raw s_barrier (NOT __syncthreads) so the compiler never
// drains vmcnt inside the loop. Staging is per-wave-quarter: no barrier
// needed for it at all.
//
// glds cannot pad LDS, so phase-A b128 reads from a linear buffer would be
// ~32-way bank-conflicted. Fix: 16B-chunk XOR swizzle applied on the
// GLOBAL source address (LDS image stays linear):
//   stage chunk sigma(g) holds global chunk g,  sigma(c)   = c ^ ((c>>2)&7)
//   write side (per-lane global src)            sigma^-1(c) = c ^ ((c>>2)&7) ^ ((c>>4)&1)
// Read banks: chunk = (4t+q) ^ (t&7) -> bank-group distinct across every
// 8-lane group (conflict-free b128).
//
// T-buffer transposes are v2's verbatim (pitch 17, <=2-way, bit-exact):
//   T1: element n at tbuf[17*(n>>4) + (n&15)]   (intra-wave; no barrier)
//   T2: element n at tbuf[17*(n&255) + (n>>8)]  (cross-wave; 2 raw barriers)

constexpr int DIM = 4096;
constexpr int PITCH = 17;      // floats per 16-float T-row (+1 pad)
constexpr int NBLOCKS = 1024;  // 4 blocks/CU x 256 CU; fully resident persistent grid

__device__ __forceinline__ void fwht16(float v[16]) {
#pragma unroll
    for (int h = 1; h < 16; h <<= 1) {
#pragma unroll
        for (int i = 0; i < 16; i += 2 * h) {
#pragma unroll
            for (int k = 0; k < h; ++k) {
                float a = v[i + k];
                float b = v[i + k + h];
                v[i + k]     = a + b;
                v[i + k + h] = a - b;
            }
        }
    }
}

// Stage one row-quarter: 4 x global_load_lds width 16. LDS dest is
// wave-uniform base + lane*16 (linear); global src carries the sigma^-1
// chunk swizzle per lane. Async: completion tracked only by vmcnt.
__device__ __forceinline__ void stage_quarter(const float* gsrc_base, float* lds_base) {
#pragma unroll
    for (int i = 0; i < 4; ++i) {
        __builtin_amdgcn_global_load_lds(
            (const __attribute__((address_space(1))) float*)(gsrc_base + i * 256),
            (__attribute__((address_space(3))) float*)(lds_base + i * 256), 16, 0, 0);
    }
}

__global__ __launch_bounds__(256, 4) void fwht4096_kernel(const float* __restrict__ x,
                                                          float* __restrict__ y,
                                                          int nrows) {
    __shared__ __align__(16) float stage[DIM];    // 16,384 B, linear + sigma chunks
    __shared__ float tbuf[PITCH * 256];           // 17,408 B
    const int t = threadIdx.x;                    // 0..255
    const int w = t >> 6;                         // wave id 0..3
    const int l = t & 63;                         // lane id
    const int t_hi = t >> 4;
    const int t_lo = t & 15;
    // sigma^-1 within a 64-chunk (1 KiB) segment: only bits 0-4 of l involved
    const int swz = l ^ ((l >> 2) & 7) ^ ((l >> 4) & 1);

    float* my_stage = stage + w * 1024;           // wave's quarter (floats)
    const int g_off = w * 1024 + swz * 4;         // per-lane float offset in row

    long long row = blockIdx.x;                   // grid <= nrows: valid
    stage_quarter(x + row * DIM + g_off, my_stage);
    asm volatile("s_waitcnt vmcnt(0)" ::: "memory");  // prologue drain (once)

    for (; row < nrows; row += NBLOCKS) {
        // Steady state: 4 glds (oldest) + 16 nt-stores (newer) outstanding.
        // vmcnt(16) -> the 4 oldest (this row's staging) have retired.
        // Iter 1: prologue drained to 0, passes trivially with valid data.
        asm volatile("s_waitcnt vmcnt(16)" ::: "memory");
        __builtin_amdgcn_sched_barrier(0);

        // ---- phase A inputs: thread t reads global chunks 4t..4t+3 at
        //      stage chunk (4t+q)^(t&7); b128, conflict-free by sigma ----
        float v[16];
#pragma unroll
        for (int q = 0; q < 4; ++q) {
            const int chunk = (4 * t + q) ^ (t & 7);
            float4 d = *reinterpret_cast<const float4*>(stage + 4 * chunk);
            v[4 * q + 0] = d.x;
            v[4 * q + 1] = d.y;
            v[4 * q + 2] = d.z;
            v[4 * q + 3] = d.w;
        }

        // ---- phase A: bits 0..3 (n = 16t + j) ----
        fwht16(v);

        // All staging reads retired, then DMA the NEXT row into this
        // wave's quarter; in flight until next loop top (whole iteration).
        asm volatile("s_waitcnt lgkmcnt(0)" ::: "memory");
        __builtin_amdgcn_sched_barrier(0);
        {
            const long long nrow = row + NBLOCKS;
            if (nrow < nrows) stage_quarter(x + nrow * DIM + g_off, my_stage);
        }
        __builtin_amdgcn_sched_barrier(0);

        // ---- transpose 1 (intra-wave: rows [64w,64w+64) only) ----
        {
            float* wp = tbuf + PITCH * t;
#pragma unroll
            for (int j = 0; j < 16; ++j) wp[j] = v[j];
        }
        // read n' = (t_hi<<8)|(j<<4)|t_lo -> 272*t_hi + 17*j + t_lo
        // (same-wave ds_write->ds_read: compiler's lgkm wait suffices)
        {
            const float* rp = tbuf + (PITCH * 16) * t_hi + t_lo;
#pragma unroll
            for (int j = 0; j < 16; ++j) v[j] = rp[PITCH * j];
        }

        // ---- phase B: bits 4..7 ----
        fwht16(v);

        // T2 writes span all waves' T1 regions: barrier (raw; no vm drain).
        asm volatile("" ::: "memory");
        __builtin_amdgcn_s_barrier();
        asm volatile("" ::: "memory");

        // ---- transpose 2: value j (n' = (t_hi<<8)|(j<<4)|t_lo) at
        //      272*j + 17*t_lo + t_hi ----
        {
            float* wp = tbuf + PITCH * t_lo + t_hi;
#pragma unroll
            for (int j = 0; j < 16; ++j) wp[(PITCH * 16) * j] = v[j];
        }
        // cross-wave ds_write -> ds_read: drain lgkm, then barrier
        asm volatile("s_waitcnt lgkmcnt(0)" ::: "memory");
        __builtin_amdgcn_s_barrier();
        asm volatile("" ::: "memory");
        // read n'' = (j<<8)|t -> 17*t + j (contiguous)
        {
            const float* rp = tbuf + PITCH * t;
#pragma unroll
            for (int j = 0; j < 16; ++j) v[j] = rp[j];
        }

        // ---- phase C: bits 8..11 ----
        fwht16(v);

        // ---- scale + 16 nontemporal dword stores (the vmcnt(16) budget) ----
        const float scale = 0x1p-39f;  // 2^-(L(L+1)/4), L = 12
        float* dst = y + row * DIM + t;
#pragma unroll
        for (int j = 0; j < 16; ++j) {
            __builtin_nontemporal_store(v[j] * scale, dst + j * 256);
        }
    }
}

extern "C" void kernel_launch(void* const* d_in, const int* in_sizes, int n_in,
                              void* d_out, int out_size, void* d_ws, size_t ws_size,
                              hipStream_t stream) {
    const float* x = (const float*)d_in[0];
    float* y = (float*)d_out;
    const int nrows = in_sizes[0] / DIM;  // 8192
    const int grid = nrows < NBLOCKS ? nrows : NBLOCKS;
    fwht4096_kernel<<<grid, 256, 0, stream>>>(x, y, nrows);
}